// Round 17
// baseline (235.041 us; speedup 1.0000x reference)
//
#include <hip/hip_runtime.h>
#include <hip/hip_bf16.h>
#include <cstdint>
#include <cstddef>

#define NN 4096

typedef float f32x4 __attribute__((ext_vector_type(4)));
typedef short s16x8 __attribute__((ext_vector_type(8)));

// ---------- prep: bit-plane mask maskT[chunk][d] (bit i = row sbase+i); no atomics ----------
__global__ __launch_bounds__(256) void k_prep(const float* __restrict__ K,
                                              unsigned long long* __restrict__ maskT) {
  const int lane = threadIdx.x & 63;
  const int wv = threadIdx.x >> 6;
  const int d0 = blockIdx.x * 256 + lane * 4;      // each lane owns 4 columns
  const int sbase = blockIdx.y * 256 + wv * 64;    // this wave's 64-row chunk
  const int chunk = blockIdx.y * 4 + wv;
  unsigned long long w0 = 0, w1 = 0, w2 = 0, w3 = 0;
#pragma unroll 8
  for (int i = 0; i < 64; ++i) {
    const float4 kv = *(const float4*)(K + (size_t)(sbase + i) * NN + d0);
    w0 |= ((unsigned long long)(kv.x != 0.0f)) << i;
    w1 |= ((unsigned long long)(kv.y != 0.0f)) << i;
    w2 |= ((unsigned long long)(kv.z != 0.0f)) << i;
    w3 |= ((unsigned long long)(kv.w != 0.0f)) << i;
  }
  unsigned long long* mp = maskT + (size_t)chunk * NN + d0;
  mp[0] = w0; mp[1] = w1; mp[2] = w2; mp[3] = w3;
}

// ---------- ONE-WAVE register Sinkhorn, potentials form ----------
// Lane l holds xR[j]=S0[l][j] and xC[j]=S0[j][l] (pre-scaled by 1/tau) in VGPRs.
// Per pass: broadcast current potential through a 64-float LDS scratch (1 write +
// 16 uniform b128 reads, same-wave lgkmcnt ordering). NO barriers, NO readlane.
// Exit: lane l holds duals U[l], V[l]; log-normalized matrix = S0 - U[i] - V[j].
__device__ __forceinline__ void sinkhorn_w1(const float (&xR)[64], const float (&xC)[64],
    float& U, float& V, float* __restrict__ pot, int l) {
  U = 0.f; V = 0.f;
#pragma unroll 1
  for (int it = 0; it < 20; ++it) {
    const bool row = (it & 1) == 0;
    pot[l] = row ? V : U;
    asm volatile("s_waitcnt lgkmcnt(0)" ::: "memory");
    float t[64];
    if (row) {
#pragma unroll
      for (int q = 0; q < 16; ++q) {
        const f32x4 p = *(const f32x4*)&pot[4 * q];   // uniform b128 broadcast
#pragma unroll
        for (int i = 0; i < 4; ++i) t[4 * q + i] = xR[4 * q + i] - p[i];
      }
    } else {
#pragma unroll
      for (int q = 0; q < 16; ++q) {
        const f32x4 p = *(const f32x4*)&pot[4 * q];
#pragma unroll
        for (int i = 0; i < 4; ++i) t[4 * q + i] = xC[4 * q + i] - p[i];
      }
    }
    float m0 = t[0], m1 = t[1], m2 = t[2], m3 = t[3];
#pragma unroll
    for (int j = 4; j < 64; j += 4) {
      m0 = fmaxf(m0, t[j]);     m1 = fmaxf(m1, t[j + 1]);
      m2 = fmaxf(m2, t[j + 2]); m3 = fmaxf(m3, t[j + 3]);
    }
    const float mx = fmaxf(fmaxf(m0, m1), fmaxf(m2, m3));
    float s0 = 0.f, s1 = 0.f, s2 = 0.f, s3 = 0.f;
#pragma unroll
    for (int j = 0; j < 64; j += 4) {
      s0 += __expf(t[j] - mx);     s1 += __expf(t[j + 1] - mx);
      s2 += __expf(t[j + 2] - mx); s3 += __expf(t[j + 3] - mx);
    }
    const float lse = mx + __logf((s0 + s1) + (s2 + s3));
    if (row) U = lse; else V = lse;
  }
}

// ---------- layer-0 transform: deg from maskT popcounts, disv, g hi/lo, xselfT ----------
__global__ __launch_bounds__(256) void k_xform0(const float* __restrict__ K,
    const unsigned long long* __restrict__ maskT,
    const float* __restrict__ cw, const float* __restrict__ cb,
    const float* __restrict__ sw, const float* __restrict__ sb,
    float* __restrict__ disv,
    __hip_bfloat16* __restrict__ gHi, __hip_bfloat16* __restrict__ gLo,
    float* __restrict__ xselfT) {
  __shared__ float pdeg[4][64];
  const int lane = threadIdx.x & 63;
  const int wv = threadIdx.x >> 6;
  const int s = blockIdx.x * 64 + lane;
  unsigned cnt = 0;
#pragma unroll
  for (int q = 0; q < 16; ++q)
    cnt += (unsigned)__popcll(maskT[(size_t)(wv * 16 + q) * NN + s]);
  pdeg[wv][lane] = (float)cnt;
  __syncthreads();
  const float ds = rsqrtf(pdeg[0][lane] + pdeg[1][lane] + pdeg[2][lane] + pdeg[3][lane]);
  if (wv == 0) disv[s] = ds;
  const float xv = K[(size_t)s * NN + s];          // diag(K)
#pragma unroll
  for (int i = 0; i < 16; ++i) {
    const int c = wv * 16 + i;
    const float gv = ds * xv * cw[c];
    const __hip_bfloat16 hi = __float2bfloat16(gv);
    gHi[(size_t)c * NN + s] = hi;
    gLo[(size_t)c * NN + s] = __float2bfloat16(gv - __bfloat162float(hi));
    xselfT[(size_t)c * NN + s] = xv * sw[c] + sb[c] + cb[c];
  }
}

// ---------- layer transform: wave0 1-wave sinkhorn CONCURRENT with waves1-4 FMA ----------
// grid (64, 2): blockIdx.x = s-tile, blockIdx.y = 32-channel half. 320 threads (5 waves).
__global__ __launch_bounds__(320, 2) void k_xform(const float* __restrict__ v,
    const float* __restrict__ vT,
    const float* __restrict__ xoutT, const float* __restrict__ disv,
    const float* __restrict__ cw, const float* __restrict__ cb,
    const float* __restrict__ sw, const float* __restrict__ sb,
    __hip_bfloat16* __restrict__ gHi, __hip_bfloat16* __restrict__ gLo,
    float* __restrict__ xselfT) {
  __shared__ __align__(16) float pot[64];
  __shared__ __align__(16) float uW[64], vW[64];
  __shared__ float xt[64][64];                     // raw xout
  __shared__ float wcl[64 * 32], wsl[64 * 32];     // [k][c-local]
  const int tid = threadIdx.x;
  const int l = tid & 63;
  const int w = tid >> 6;                          // 0..4
  const int s = blockIdx.x * 64 + l;
  const int cbase = blockIdx.y * 32;
  float xR[64], xC[64];
  if (w == 0) {                                    // sinkhorn input into registers
#pragma unroll
    for (int q = 0; q < 16; ++q) {
      *(f32x4*)&xR[4 * q] = *(const f32x4*)&v[l * 64 + 4 * q] * 20.0f;
      *(f32x4*)&xC[4 * q] = *(const f32x4*)&vT[l * 64 + 4 * q] * 20.0f;
    }
  } else {                                         // stage xt rows + weight slab
    const int ww = w - 1;                          // 0..3
#pragma unroll
    for (int r = 0; r < 16; ++r)
      xt[ww * 16 + r][l] = xoutT[(size_t)(ww * 16 + r) * NN + s];
#pragma unroll
    for (int q = 0; q < 8; ++q) {
      const int e = ww * 512 + q * 64 + l;         // e = k*32 + cl
      const int k = e >> 5, cl = e & 31;
      wcl[e] = cw[k * 64 + cbase + cl];
      wsl[e] = sw[k * 64 + cbase + cl];
    }
  }
  __syncthreads();                                 // B0: staging done
  float accC[8], accS[8], csum[8], ssum[8];
  if (w == 0) {                                    // serial sinkhorn, overlapped w/ FMA
    float U, V;
    sinkhorn_w1(xR, xC, U, V, pot, l);
    uW[l] = U; vW[l] = V;
    asm volatile("s_waitcnt lgkmcnt(0)" ::: "memory");
  } else {                                         // FMA: 8 channels per wave
    const int cl0 = (w - 1) * 8;
#pragma unroll
    for (int i = 0; i < 8; ++i) { accC[i] = 0.f; accS[i] = 0.f; csum[i] = 0.f; ssum[i] = 0.f; }
    for (int k = 0; k < 64; ++k) {
      const float xv = xt[k][l];
      const f32x4 wcA = *(const f32x4*)&wcl[k * 32 + cl0];
      const f32x4 wcB = *(const f32x4*)&wcl[k * 32 + cl0 + 4];
      const f32x4 wsA = *(const f32x4*)&wsl[k * 32 + cl0];
      const f32x4 wsB = *(const f32x4*)&wsl[k * 32 + cl0 + 4];
#pragma unroll
      for (int i = 0; i < 4; ++i) {
        accC[i]     = fmaf(xv, wcA[i], accC[i]);     csum[i]     += wcA[i];
        accC[i + 4] = fmaf(xv, wcB[i], accC[i + 4]); csum[i + 4] += wcB[i];
        accS[i]     = fmaf(xv, wsA[i], accS[i]);     ssum[i]     += wsA[i];
        accS[i + 4] = fmaf(xv, wsB[i], accS[i + 4]); ssum[i + 4] += wsB[i];
      }
    }
  }
  __syncthreads();                                 // B1: duals + accs ready
  if (w > 0) {
    const int bx = blockIdx.x;
    const float skv = __expf(20.0f * v[bx * 64 + l] - uW[bx] - vW[l]);
    const float ds = disv[s];
    const int cl0 = (w - 1) * 8;
#pragma unroll
    for (int i = 0; i < 8; ++i) {
      const int c = cbase + cl0 + i;
      const float gv = ds * (accC[i] + skv * csum[i]);     // rank-1 sk fold
      const __hip_bfloat16 hi = __float2bfloat16(gv);
      gHi[(size_t)c * NN + s] = hi;
      gLo[(size_t)c * NN + s] = __float2bfloat16(gv - __bfloat162float(hi));
      xselfT[(size_t)c * NN + s] = accS[i] + skv * ssum[i] + sb[c] + cb[c];
    }
  }
}

// ---------- MFMA masked aggregation + in-block combine (+ final-score fold on last layer) ----------
__global__ __launch_bounds__(512) void k_agg(const unsigned long long* __restrict__ maskT,
    const __hip_bfloat16* __restrict__ gHi, const __hip_bfloat16* __restrict__ gLo,
    const float* __restrict__ xselfT, const float* __restrict__ disv,
    const float* __restrict__ kw, const float* __restrict__ kb,
    const float* __restrict__ fw, const float* __restrict__ fb,
    float* __restrict__ xoutT, float* __restrict__ v, float* __restrict__ vT,
    float* __restrict__ sbF, float* __restrict__ sbFT) {
  const int tid = threadIdx.x;
  const int lane = tid & 63;
  const int wv = tid >> 6;           // 0..7
  const int mtile = wv & 3;          // channel 16-group
  const int ks = wv >> 2;            // K-split 0/1
  const int l15 = lane & 15;
  const int h = lane >> 4;           // 0..3
  const int d = blockIdx.x * 16 + l15;
  const int ch = mtile * 16 + l15;   // A-operand row (channel)
  const short* __restrict__ gh = (const short*)gHi;
  const short* __restrict__ gl = (const short*)gLo;
  f32x4 acch = {0.f, 0.f, 0.f, 0.f};
  f32x4 accl = {0.f, 0.f, 0.f, 0.f};
  const int c0 = ks * 32;
#pragma unroll 4
  for (int c = c0; c < c0 + 32; ++c) {
    const unsigned long long w = maskT[(size_t)c * NN + d];
    const unsigned half0 = (unsigned)w, half1 = (unsigned)(w >> 32);
#pragma unroll
    for (int t = 0; t < 2; ++t) {
      const unsigned half = t ? half1 : half0;
      const unsigned hb = (half >> (8 * h)) & 0xFFu;
      s16x8 bfr;
#pragma unroll
      for (int j = 0; j < 8; ++j)
        bfr[j] = (short)(((hb >> j) & 1u) * 0x3F80u);   // bit -> bf16 1.0/0.0
      const size_t abase = (size_t)ch * NN + (size_t)(c * 64 + t * 32 + 8 * h);
      const s16x8 ah = *(const s16x8*)(gh + abase);
      const s16x8 al = *(const s16x8*)(gl + abase);
      acch = __builtin_amdgcn_mfma_f32_16x16x32_bf16(ah, bfr, acch, 0, 0, 0);
      accl = __builtin_amdgcn_mfma_f32_16x16x32_bf16(al, bfr, accl, 0, 0, 0);
    }
  }
  __shared__ float rbuf[4][64][5];
  __shared__ float vred[16][17];
  __shared__ float vred2[16][17];
  f32x4 tot;
#pragma unroll
  for (int r = 0; r < 4; ++r) tot[r] = acch[r] + accl[r];
  if (ks == 1) {
#pragma unroll
    for (int r = 0; r < 4; ++r) rbuf[mtile][lane][r] = tot[r];
  }
  __syncthreads();
  if (ks == 0) {
    // C/D layout: col = lane&15 (=d), row = (lane>>4)*4 + reg (=channel in mtile)
    const float dd = disv[d];
    float p = 0.f, p2 = 0.f;
#pragma unroll
    for (int r = 0; r < 4; ++r) {
      const int chr = mtile * 16 + h * 4 + r;
      const float xo = xselfT[(size_t)chr * NN + d] + dd * (tot[r] + rbuf[mtile][lane][r]);
      xoutT[(size_t)chr * NN + d] = xo;
      p = fmaf(xo, kw[chr], p);
      p2 = fmaf(xo, fw[chr], p2);    // final-score partial (used only on last layer)
    }
    vred[l15][mtile * 4 + h] = p;
    vred2[l15][mtile * 4 + h] = p2;
  }
  __syncthreads();
  if (tid < 16) {
    float sum = kb[0];
#pragma unroll
    for (int q = 0; q < 16; ++q) sum += vred[tid][q];
    const int d2 = blockIdx.x * 16 + tid;
    v[d2] = sum;                                   // flat: row-major S0
    vT[(d2 & 63) * 64 + (d2 >> 6)] = sum;          // transposed
    if (sbF != nullptr) {                          // last layer: base scores, both layouts
      float sum2 = fb[0];
#pragma unroll
      for (int q = 0; q < 16; ++q) sum2 += vred2[tid][q];
      sbF[d2] = sum2;
      sbFT[(d2 & 63) * 64 + (d2 >> 6)] = sum2;
    }
  }
}

// ---------- final: 1 wave. sinkhorn(sk2) -> in-register fold -> sinkhorn -> out ----------
__global__ __launch_bounds__(64, 1) void k_final(const float* __restrict__ v,
    const float* __restrict__ vT, const float* __restrict__ sbF,
    const float* __restrict__ sbFT, const float* __restrict__ fw,
    float* __restrict__ out) {
  __shared__ __align__(16) float potA[64], potB[64];
  const int l = threadIdx.x;
  float xR[64], xC[64];
#pragma unroll
  for (int q = 0; q < 16; ++q) {
    *(f32x4*)&xR[4 * q] = *(const f32x4*)&v[l * 64 + 4 * q] * 20.0f;
    *(f32x4*)&xC[4 * q] = *(const f32x4*)&vT[l * 64 + 4 * q] * 20.0f;
  }
  float sumw = 0.f;
#pragma unroll
  for (int k = 0; k < 64; ++k) sumw += fw[k];      // uniform loads
  float U1, V1;
  sinkhorn_w1(xR, xC, U1, V1, potA, l);            // sk2 duals
  potA[l] = U1; potB[l] = V1;                      // broadcast both duals
  asm volatile("s_waitcnt lgkmcnt(0)" ::: "memory");
  // fold in place: xR[j] <- S[l][j], xC[j] <- S[j][l] of the final score matrix
  // S[i1][i2] = (scores[i2*64+i1] + sk2[i1][i2]*sumw)*20, logsk2[i1][i2]=20v[i1*64+i2]-U1[i1]-V1[i2]
#pragma unroll
  for (int q = 0; q < 16; ++q) {
    const f32x4 Ub = *(const f32x4*)&potA[4 * q];
    const f32x4 Vb = *(const f32x4*)&potB[4 * q];
    const f32x4 sT = *(const f32x4*)&sbFT[l * 64 + 4 * q];
    const f32x4 sF = *(const f32x4*)&sbF[l * 64 + 4 * q];
#pragma unroll
    for (int i = 0; i < 4; ++i) {
      const int j = 4 * q + i;
      const float a = xR[j], b = xC[j];
      xR[j] = (sT[i] + __expf(b - Ub[i] - V1) * sumw) * 20.0f;   // S[l][j]
      xC[j] = (sF[i] + __expf(a - U1 - Vb[i]) * sumw) * 20.0f;   // S[j][l]
    }
  }
  float U2, V2;
  sinkhorn_w1(xR, xC, U2, V2, potA, l);
  potA[l] = U2;
  asm volatile("s_waitcnt lgkmcnt(0)" ::: "memory");
#pragma unroll
  for (int q = 0; q < 16; ++q) {
    const f32x4 Ub = *(const f32x4*)&potA[4 * q];
#pragma unroll
    for (int i = 0; i < 4; ++i)                    // out[i1*64+i2], i2 = l (coalesced)
      out[(4 * q + i) * 64 + l] = __expf(xC[4 * q + i] - Ub[i] - V2);
  }
}

extern "C" void kernel_launch(void* const* d_in, const int* in_sizes, int n_in,
                              void* d_out, int out_size, void* d_ws, size_t ws_size,
                              hipStream_t stream) {
  const float* K = (const float*)d_in[0];
  const float* cw[3] = {(const float*)d_in[4],  (const float*)d_in[10], (const float*)d_in[16]};
  const float* cb[3] = {(const float*)d_in[5],  (const float*)d_in[11], (const float*)d_in[17]};
  const float* sw[3] = {(const float*)d_in[6],  (const float*)d_in[12], (const float*)d_in[18]};
  const float* sb[3] = {(const float*)d_in[7],  (const float*)d_in[13], (const float*)d_in[19]};
  const float* kw[3] = {(const float*)d_in[8],  (const float*)d_in[14], (const float*)d_in[20]};
  const float* kb[3] = {(const float*)d_in[9],  (const float*)d_in[15], (const float*)d_in[21]};
  const float* fw = (const float*)d_in[22];
  const float* fb = (const float*)d_in[23];
  float* out = (float*)d_out;

  char* ws = (char*)d_ws;
  const size_t KB = 1024, MB = 1024 * 1024;
  float* disv               = (float*)(ws + 0);                   // 16 KB
  float* v                  = (float*)(ws + 16 * KB);             // 16 KB
  float* vT                 = (float*)(ws + 32 * KB);             // 16 KB
  float* sbF                = (float*)(ws + 48 * KB);             // 16 KB
  unsigned long long* maskT = (unsigned long long*)(ws + 64 * KB);// 2 MB
  __hip_bfloat16* gHi       = (__hip_bfloat16*)(ws + 64 * KB + 2 * MB);            // 512 KB
  __hip_bfloat16* gLo       = (__hip_bfloat16*)(ws + 64 * KB + 2 * MB + 512 * KB); // 512 KB
  float* xselfT             = (float*)(ws + 64 * KB + 3 * MB);    // 1 MB
  float* xoutT              = (float*)(ws + 64 * KB + 4 * MB);    // 1 MB
  float* sbFT               = (float*)(ws + 64 * KB + 5 * MB);    // 16 KB
  (void)in_sizes; (void)n_in; (void)out_size; (void)ws_size;

  k_prep<<<dim3(16, 16), 256, 0, stream>>>(K, maskT);
  k_xform0<<<64, 256, 0, stream>>>(K, maskT, cw[0], cb[0], sw[0], sb[0],
                                   disv, gHi, gLo, xselfT);
  k_agg<<<256, 512, 0, stream>>>(maskT, gHi, gLo, xselfT, disv, kw[0], kb[0],
                                 fw, fb, xoutT, v, vT, nullptr, nullptr);
  for (int l = 1; l < 3; ++l) {
    k_xform<<<dim3(64, 2), 320, 0, stream>>>(v, vT, xoutT, disv, cw[l], cb[l], sw[l], sb[l],
                                             gHi, gLo, xselfT);
    k_agg<<<256, 512, 0, stream>>>(maskT, gHi, gLo, xselfT, disv, kw[l], kb[l],
                                   fw, fb, xoutT, v, vT,
                                   (l == 2) ? sbF : nullptr, (l == 2) ? sbFT : nullptr);
  }
  k_final<<<1, 64, 0, stream>>>(v, vT, sbF, sbFT, fw, out);
}

// Round 18
// 207.276 us; speedup vs baseline: 1.1340x; 1.1340x over previous
//
#include <hip/hip_runtime.h>
#include <hip/hip_bf16.h>
#include <cstdint>
#include <cstddef>

#define NN 4096

typedef float f32x4 __attribute__((ext_vector_type(4)));
typedef short s16x8 __attribute__((ext_vector_type(8)));

__device__ __forceinline__ float bperm(float x, int srclane) {
  return __int_as_float(__builtin_amdgcn_ds_bpermute(srclane * 4, __float_as_int(x)));
}

// ---------- prep: bit-plane mask maskT[chunk][d] (bit i = row sbase+i); no atomics ----------
__global__ __launch_bounds__(256) void k_prep(const float* __restrict__ K,
                                              unsigned long long* __restrict__ maskT) {
  const int lane = threadIdx.x & 63;
  const int wv = threadIdx.x >> 6;
  const int d0 = blockIdx.x * 256 + lane * 4;      // each lane owns 4 columns
  const int sbase = blockIdx.y * 256 + wv * 64;    // this wave's 64-row chunk
  const int chunk = blockIdx.y * 4 + wv;
  unsigned long long w0 = 0, w1 = 0, w2 = 0, w3 = 0;
#pragma unroll 8
  for (int i = 0; i < 64; ++i) {
    const float4 kv = *(const float4*)(K + (size_t)(sbase + i) * NN + d0);
    w0 |= ((unsigned long long)(kv.x != 0.0f)) << i;
    w1 |= ((unsigned long long)(kv.y != 0.0f)) << i;
    w2 |= ((unsigned long long)(kv.z != 0.0f)) << i;
    w3 |= ((unsigned long long)(kv.w != 0.0f)) << i;
  }
  unsigned long long* mp = maskT + (size_t)chunk * NN + d0;
  mp[0] = w0; mp[1] = w1; mp[2] = w2; mp[3] = w3;
}

// ---------- 4-wave Sinkhorn, potentials form, bpermute distribution ----------
// Thread (w=tid>>6, l=tid&63) holds xR[j]=S0[l][jb+j]*20, xC[j]=S0[jb+j][l]*20 (jb=w*16).
// After the redundant combine every wave holds the full dual vector in its own lanes
// (lane l = dual[l]) -> potentials distributed by in-wave ds_bpermute (wave-uniform idx,
// no LDS round-trip, no fences). ONE barrier per iteration; partials double-buffered at
// stride 64 (2-way = free). Exit: lane l of every wave holds U[l], V[l].
__device__ __forceinline__ void sinkhorn_bp(const float (&xR)[16], const float (&xC)[16],
    float& U, float& V, float* __restrict__ pp /*2*512*/, int l, int w, int jb) {
  U = 0.f; V = 0.f;
#pragma unroll 1
  for (int it = 0; it < 20; ++it) {
    const bool row = (it & 1) == 0;
    const float src = row ? V : U;
    float t[16];
    if (row) {
#pragma unroll
      for (int j = 0; j < 16; ++j) t[j] = xR[j] - bperm(src, jb + j);
    } else {
#pragma unroll
      for (int j = 0; j < 16; ++j) t[j] = xC[j] - bperm(src, jb + j);
    }
    float a0 = fmaxf(t[0], t[1]),  a1 = fmaxf(t[2], t[3]);
    float a2 = fmaxf(t[4], t[5]),  a3 = fmaxf(t[6], t[7]);
    a0 = fmaxf(a0, fmaxf(t[8], t[9]));   a1 = fmaxf(a1, fmaxf(t[10], t[11]));
    a2 = fmaxf(a2, fmaxf(t[12], t[13])); a3 = fmaxf(a3, fmaxf(t[14], t[15]));
    const float mx = fmaxf(fmaxf(a0, a1), fmaxf(a2, a3));
    float s0 = 0.f, s1 = 0.f, s2 = 0.f, s3 = 0.f;
#pragma unroll
    for (int j = 0; j < 16; j += 4) {
      s0 += __expf(t[j] - mx);     s1 += __expf(t[j + 1] - mx);
      s2 += __expf(t[j + 2] - mx); s3 += __expf(t[j + 3] - mx);
    }
    const float sm = (s0 + s1) + (s2 + s3);
    float* buf = pp + (it & 1) * 512;
    buf[w * 64 + l] = mx;                          // stride-64: 2-way = free
    buf[256 + w * 64 + l] = sm;
    __syncthreads();
    const float m0 = buf[l],       m1 = buf[64 + l];
    const float m2 = buf[128 + l], m3 = buf[192 + l];
    const float q0 = buf[256 + l], q1 = buf[320 + l];
    const float q2 = buf[384 + l], q3 = buf[448 + l];
    const float mM = fmaxf(fmaxf(m0, m1), fmaxf(m2, m3));
    const float ss = q0 * __expf(m0 - mM) + q1 * __expf(m1 - mM)
                   + q2 * __expf(m2 - mM) + q3 * __expf(m3 - mM);
    const float lse = mM + __logf(ss);
    if (row) U = lse; else V = lse;
  }
}

// ---------- layer-0 transform: deg from maskT popcounts, disv, g hi/lo, xselfT ----------
__global__ __launch_bounds__(256) void k_xform0(const float* __restrict__ K,
    const unsigned long long* __restrict__ maskT,
    const float* __restrict__ cw, const float* __restrict__ cb,
    const float* __restrict__ sw, const float* __restrict__ sb,
    float* __restrict__ disv,
    __hip_bfloat16* __restrict__ gHi, __hip_bfloat16* __restrict__ gLo,
    float* __restrict__ xselfT) {
  __shared__ float pdeg[4][64];
  const int lane = threadIdx.x & 63;
  const int wv = threadIdx.x >> 6;
  const int s = blockIdx.x * 64 + lane;
  unsigned cnt = 0;
#pragma unroll
  for (int q = 0; q < 16; ++q)
    cnt += (unsigned)__popcll(maskT[(size_t)(wv * 16 + q) * NN + s]);
  pdeg[wv][lane] = (float)cnt;
  __syncthreads();
  const float ds = rsqrtf(pdeg[0][lane] + pdeg[1][lane] + pdeg[2][lane] + pdeg[3][lane]);
  if (wv == 0) disv[s] = ds;
  const float xv = K[(size_t)s * NN + s];          // diag(K)
#pragma unroll
  for (int i = 0; i < 16; ++i) {
    const int c = wv * 16 + i;
    const float gv = ds * xv * cw[c];
    const __hip_bfloat16 hi = __float2bfloat16(gv);
    gHi[(size_t)c * NN + s] = hi;
    gLo[(size_t)c * NN + s] = __float2bfloat16(gv - __bfloat162float(hi));
    xselfT[(size_t)c * NN + s] = xv * sw[c] + sb[c] + cb[c];
  }
}

// ---------- layer transform: bp sinkhorn + FMA + rank-1 sk fold ----------
// grid (64, 2): blockIdx.x = s-tile, blockIdx.y = 32-channel half. 256 threads.
__global__ __launch_bounds__(256, 1) void k_xform(const float* __restrict__ v,
    const float* __restrict__ vT,
    const float* __restrict__ xoutT, const float* __restrict__ disv,
    const float* __restrict__ cw, const float* __restrict__ cb,
    const float* __restrict__ sw, const float* __restrict__ sb,
    __hip_bfloat16* __restrict__ gHi, __hip_bfloat16* __restrict__ gLo,
    float* __restrict__ xselfT) {
  __shared__ __align__(16) float pp[2 * 512];
  __shared__ float xt[64][64];                     // raw xout
  __shared__ float wcl[64 * 32], wsl[64 * 32];     // [k][c-local]
  const int tid = threadIdx.x;
  const int l = tid & 63;
  const int w = tid >> 6;                          // 0..3
  const int jb = w * 16;
  const int s = blockIdx.x * 64 + l;
  const int cbase = blockIdx.y * 32;
  // ---- sinkhorn input into registers (tiny, L2-resident) ----
  float xR[16], xC[16];
#pragma unroll
  for (int q = 0; q < 4; ++q) {
    *(f32x4*)&xR[4 * q] = *(const f32x4*)&v[l * 64 + jb + 4 * q] * 20.0f;
    *(f32x4*)&xC[4 * q] = *(const f32x4*)&vT[l * 64 + jb + 4 * q] * 20.0f;
  }
  // ---- stage xt + weight slab (synced by sinkhorn's first barrier) ----
#pragma unroll
  for (int r = 0; r < 16; ++r)
    xt[w * 16 + r][l] = xoutT[(size_t)(w * 16 + r) * NN + s];
#pragma unroll
  for (int q = 0; q < 8; ++q) {
    const int e = w * 512 + q * 64 + l;            // e = k*32 + cl
    const int k = e >> 5, cl = e & 31;
    wcl[e] = cw[k * 64 + cbase + cl];
    wsl[e] = sw[k * 64 + cbase + cl];
  }
  float U, V;
  sinkhorn_bp(xR, xC, U, V, pp, l, w, jb);
  // ---- FMA: 8 channels per wave; float4 broadcast weight reads ----
  const int cl0 = w * 8;
  float accC[8], accS[8], csum[8], ssum[8];
#pragma unroll
  for (int i = 0; i < 8; ++i) { accC[i] = 0.f; accS[i] = 0.f; csum[i] = 0.f; ssum[i] = 0.f; }
  for (int k = 0; k < 64; ++k) {
    const float xv = xt[k][l];
    const f32x4 wcA = *(const f32x4*)&wcl[k * 32 + cl0];
    const f32x4 wcB = *(const f32x4*)&wcl[k * 32 + cl0 + 4];
    const f32x4 wsA = *(const f32x4*)&wsl[k * 32 + cl0];
    const f32x4 wsB = *(const f32x4*)&wsl[k * 32 + cl0 + 4];
#pragma unroll
    for (int i = 0; i < 4; ++i) {
      accC[i]     = fmaf(xv, wcA[i], accC[i]);     csum[i]     += wcA[i];
      accC[i + 4] = fmaf(xv, wcB[i], accC[i + 4]); csum[i + 4] += wcB[i];
      accS[i]     = fmaf(xv, wsA[i], accS[i]);     ssum[i]     += wsA[i];
      accS[i + 4] = fmaf(xv, wsB[i], accS[i + 4]); ssum[i + 4] += wsB[i];
    }
  }
  // ---- epilogue: sk from duals (in-wave bperm for U[bx]), rank-1 sk fold ----
  const int bx = blockIdx.x;
  const float Ubx = bperm(U, bx);                  // uniform index broadcast
  const float skv = __expf(20.0f * v[bx * 64 + l] - Ubx - V);
  const float ds = disv[s];
#pragma unroll
  for (int i = 0; i < 8; ++i) {
    const int c = cbase + cl0 + i;
    const float gv = ds * (accC[i] + skv * csum[i]);
    const __hip_bfloat16 hi = __float2bfloat16(gv);
    gHi[(size_t)c * NN + s] = hi;
    gLo[(size_t)c * NN + s] = __float2bfloat16(gv - __bfloat162float(hi));
    xselfT[(size_t)c * NN + s] = accS[i] + skv * ssum[i] + sb[c] + cb[c];
  }
}

// ---------- MFMA masked aggregation + in-block combine (+ final-score fold on last layer) ----------
__global__ __launch_bounds__(512) void k_agg(const unsigned long long* __restrict__ maskT,
    const __hip_bfloat16* __restrict__ gHi, const __hip_bfloat16* __restrict__ gLo,
    const float* __restrict__ xselfT, const float* __restrict__ disv,
    const float* __restrict__ kw, const float* __restrict__ kb,
    const float* __restrict__ fw, const float* __restrict__ fb,
    float* __restrict__ xoutT, float* __restrict__ v, float* __restrict__ vT,
    float* __restrict__ sbF) {
  const int tid = threadIdx.x;
  const int lane = tid & 63;
  const int wv = tid >> 6;           // 0..7
  const int mtile = wv & 3;          // channel 16-group
  const int ks = wv >> 2;            // K-split 0/1
  const int l15 = lane & 15;
  const int h = lane >> 4;           // 0..3
  const int d = blockIdx.x * 16 + l15;
  const int ch = mtile * 16 + l15;   // A-operand row (channel)
  const short* __restrict__ gh = (const short*)gHi;
  const short* __restrict__ gl = (const short*)gLo;
  f32x4 acch = {0.f, 0.f, 0.f, 0.f};
  f32x4 accl = {0.f, 0.f, 0.f, 0.f};
  const int c0 = ks * 32;
#pragma unroll 4
  for (int c = c0; c < c0 + 32; ++c) {
    const unsigned long long w = maskT[(size_t)c * NN + d];
    const unsigned half0 = (unsigned)w, half1 = (unsigned)(w >> 32);
#pragma unroll
    for (int t = 0; t < 2; ++t) {
      const unsigned half = t ? half1 : half0;
      const unsigned hb = (half >> (8 * h)) & 0xFFu;
      s16x8 bfr;
#pragma unroll
      for (int j = 0; j < 8; ++j)
        bfr[j] = (short)(((hb >> j) & 1u) * 0x3F80u);   // bit -> bf16 1.0/0.0
      const size_t abase = (size_t)ch * NN + (size_t)(c * 64 + t * 32 + 8 * h);
      const s16x8 ah = *(const s16x8*)(gh + abase);
      const s16x8 al = *(const s16x8*)(gl + abase);
      acch = __builtin_amdgcn_mfma_f32_16x16x32_bf16(ah, bfr, acch, 0, 0, 0);
      accl = __builtin_amdgcn_mfma_f32_16x16x32_bf16(al, bfr, accl, 0, 0, 0);
    }
  }
  __shared__ float rbuf[4][64][5];
  __shared__ float vred[16][17];
  __shared__ float vred2[16][17];
  f32x4 tot;
#pragma unroll
  for (int r = 0; r < 4; ++r) tot[r] = acch[r] + accl[r];
  if (ks == 1) {
#pragma unroll
    for (int r = 0; r < 4; ++r) rbuf[mtile][lane][r] = tot[r];
  }
  __syncthreads();
  if (ks == 0) {
    // C/D layout: col = lane&15 (=d), row = (lane>>4)*4 + reg (=channel in mtile)
    const float dd = disv[d];
    float p = 0.f, p2 = 0.f;
#pragma unroll
    for (int r = 0; r < 4; ++r) {
      const int chr = mtile * 16 + h * 4 + r;
      const float xo = xselfT[(size_t)chr * NN + d] + dd * (tot[r] + rbuf[mtile][lane][r]);
      xoutT[(size_t)chr * NN + d] = xo;
      p = fmaf(xo, kw[chr], p);
      p2 = fmaf(xo, fw[chr], p2);    // final-score partial (used only on last layer)
    }
    vred[l15][mtile * 4 + h] = p;
    vred2[l15][mtile * 4 + h] = p2;
  }
  __syncthreads();
  if (tid < 16) {
    float sum = kb[0];
#pragma unroll
    for (int q = 0; q < 16; ++q) sum += vred[tid][q];
    const int d2 = blockIdx.x * 16 + tid;
    v[d2] = sum;                                   // flat: row-major S0
    vT[(d2 & 63) * 64 + (d2 >> 6)] = sum;          // transposed
    if (sbF != nullptr) {                          // last layer: base scores, flat
      float sum2 = fb[0];
#pragma unroll
      for (int q = 0; q < 16; ++q) sum2 += vred2[tid][q];
      sbF[d2] = sum2;
    }
  }
}

// ---------- final: bp sinkhorn(sk2) -> fold (LDS swap) -> bp sinkhorn -> out ----------
__global__ __launch_bounds__(256, 1) void k_final(const float* __restrict__ v,
    const float* __restrict__ vT, const float* __restrict__ sbF,
    const float* __restrict__ fw, float* __restrict__ out) {
  __shared__ __align__(16) float pp[2 * 512];
  __shared__ __align__(16) float scR[64 * 68];     // folded S row-major
  __shared__ __align__(16) float scT[64 * 68];     // folded S col-major
  __shared__ float fwl[64];
  const int tid = threadIdx.x;
  const int l = tid & 63;
  const int w = tid >> 6;
  const int jb = w * 16;
  float xR[16], xC[16];
#pragma unroll
  for (int q = 0; q < 4; ++q) {
    *(f32x4*)&xR[4 * q] = *(const f32x4*)&v[l * 64 + jb + 4 * q] * 20.0f;
    *(f32x4*)&xC[4 * q] = *(const f32x4*)&vT[l * 64 + jb + 4 * q] * 20.0f;
  }
  if (tid < 64) fwl[tid] = fw[tid];
  float U1, V1;
  sinkhorn_bp(xR, xC, U1, V1, pp, l, w, jb);       // sk2 duals (lane l of every wave)
  float sumw = 0.f;
#pragma unroll
  for (int k = 0; k < 64; ++k) sumw += fwl[k];     // broadcast reads
  // ---- fold: S[i1=n&63][i2=n>>6] = (scores[n] + sk2[n]*sumw)*20 ----
#pragma unroll
  for (int k = 0; k < 16; ++k) {
    const int n = k * 256 + tid;                   // r2 = n>>6 uniform per iter
    const int r2 = 4 * k + w;
    const float u1r2 = bperm(U1, r2);              // in-wave uniform broadcast
    const float sk2 = __expf(20.0f * v[n] - u1r2 - V1);
    const float val = (sbF[n] + sk2 * sumw) * 20.0f;
    scR[l * 68 + r2] = val;                        // S[i1=l][i2=r2]
    scT[r2 * 68 + l] = val;
  }
  __syncthreads();
  // ---- reload regs in both orientations (stride-68 b128: conflict-free) ----
#pragma unroll
  for (int q = 0; q < 4; ++q) {
    *(f32x4*)&xR[4 * q] = *(const f32x4*)&scR[l * 68 + jb + 4 * q];
    *(f32x4*)&xC[4 * q] = *(const f32x4*)&scT[l * 68 + jb + 4 * q];
  }
  float U2, V2;
  sinkhorn_bp(xR, xC, U2, V2, pp, l, w, jb);
  // ---- output: out[i1*64+i2] = exp(S - U2[i1] - V2[i2]) ----
#pragma unroll
  for (int q = 0; q < 16; ++q) {
    const int e = q * 256 + tid;                   // i1 = 4q+w (uniform), i2 = l
    const int i1 = 4 * q + w;
    const float u2i1 = bperm(U2, i1);
    out[e] = __expf(scR[i1 * 68 + l] - u2i1 - V2);
  }
}

extern "C" void kernel_launch(void* const* d_in, const int* in_sizes, int n_in,
                              void* d_out, int out_size, void* d_ws, size_t ws_size,
                              hipStream_t stream) {
  const float* K = (const float*)d_in[0];
  const float* cw[3] = {(const float*)d_in[4],  (const float*)d_in[10], (const float*)d_in[16]};
  const float* cb[3] = {(const float*)d_in[5],  (const float*)d_in[11], (const float*)d_in[17]};
  const float* sw[3] = {(const float*)d_in[6],  (const float*)d_in[12], (const float*)d_in[18]};
  const float* sb[3] = {(const float*)d_in[7],  (const float*)d_in[13], (const float*)d_in[19]};
  const float* kw[3] = {(const float*)d_in[8],  (const float*)d_in[14], (const float*)d_in[20]};
  const float* kb[3] = {(const float*)d_in[9],  (const float*)d_in[15], (const float*)d_in[21]};
  const float* fw = (const float*)d_in[22];
  const float* fb = (const float*)d_in[23];
  float* out = (float*)d_out;

  char* ws = (char*)d_ws;
  const size_t KB = 1024, MB = 1024 * 1024;
  float* disv               = (float*)(ws + 0);                   // 16 KB
  float* v                  = (float*)(ws + 16 * KB);             // 16 KB
  float* vT                 = (float*)(ws + 32 * KB);             // 16 KB
  float* sbF                = (float*)(ws + 48 * KB);             // 16 KB
  unsigned long long* maskT = (unsigned long long*)(ws + 64 * KB);// 2 MB
  __hip_bfloat16* gHi       = (__hip_bfloat16*)(ws + 64 * KB + 2 * MB);            // 512 KB
  __hip_bfloat16* gLo       = (__hip_bfloat16*)(ws + 64 * KB + 2 * MB + 512 * KB); // 512 KB
  float* xselfT             = (float*)(ws + 64 * KB + 3 * MB);    // 1 MB
  float* xoutT              = (float*)(ws + 64 * KB + 4 * MB);    // 1 MB
  (void)in_sizes; (void)n_in; (void)out_size; (void)ws_size;

  k_prep<<<dim3(16, 16), 256, 0, stream>>>(K, maskT);
  k_xform0<<<64, 256, 0, stream>>>(K, maskT, cw[0], cb[0], sw[0], sb[0],
                                   disv, gHi, gLo, xselfT);
  k_agg<<<256, 512, 0, stream>>>(maskT, gHi, gLo, xselfT, disv, kw[0], kb[0],
                                 fw, fb, xoutT, v, vT, nullptr);
  for (int l = 1; l < 3; ++l) {
    k_xform<<<dim3(64, 2), 256, 0, stream>>>(v, vT, xoutT, disv, cw[l], cb[l], sw[l], sb[l],
                                             gHi, gLo, xselfT);
    k_agg<<<256, 512, 0, stream>>>(maskT, gHi, gLo, xselfT, disv, kw[l], kb[l],
                                   fw, fb, xoutT, v, vT, (l == 2) ? sbF : nullptr);
  }
  k_final<<<1, 256, 0, stream>>>(v, vT, sbF, fw, out);
}

// Round 19
// 198.279 us; speedup vs baseline: 1.1854x; 1.0454x over previous
//
#include <hip/hip_runtime.h>
#include <hip/hip_bf16.h>
#include <cstdint>
#include <cstddef>

#define NN 4096

typedef float f32x4 __attribute__((ext_vector_type(4)));
typedef short s16x8 __attribute__((ext_vector_type(8)));

__device__ __forceinline__ float rdlane(float x, int lane) {
  return __int_as_float(__builtin_amdgcn_readlane(__float_as_int(x), lane));
}

// ---------- prep: bit-plane mask maskT[chunk][d] (bit i = row sbase+i); no atomics ----------
__global__ __launch_bounds__(256) void k_prep(const float* __restrict__ K,
                                              unsigned long long* __restrict__ maskT) {
  const int lane = threadIdx.x & 63;
  const int wv = threadIdx.x >> 6;
  const int d0 = blockIdx.x * 256 + lane * 4;      // each lane owns 4 columns
  const int sbase = blockIdx.y * 256 + wv * 64;    // this wave's 64-row chunk
  const int chunk = blockIdx.y * 4 + wv;
  unsigned long long w0 = 0, w1 = 0, w2 = 0, w3 = 0;
#pragma unroll 8
  for (int i = 0; i < 64; ++i) {
    const float4 kv = *(const float4*)(K + (size_t)(sbase + i) * NN + d0);
    w0 |= ((unsigned long long)(kv.x != 0.0f)) << i;
    w1 |= ((unsigned long long)(kv.y != 0.0f)) << i;
    w2 |= ((unsigned long long)(kv.z != 0.0f)) << i;
    w3 |= ((unsigned long long)(kv.w != 0.0f)) << i;
  }
  unsigned long long* mp = maskT + (size_t)chunk * NN + d0;
  mp[0] = w0; mp[1] = w1; mp[2] = w2; mp[3] = w3;
}

// ---------- 4-wave Sinkhorn, potentials form, SGPR-readlane distribution ----------
// Thread (w, l) holds xR[j]=S0[l][jb+j]*20, xC[j]=S0[jb+j][l]*20, jb = wu*16 where
// wu = readfirstlane(tid>>6) -- provably wave-uniform so readlane(reg, jb+j) compiles
// to v_readlane_b32 with SGPR index (no waterfall, no LDS, no fences). After the
// redundant combine every wave holds the full dual vector in its own lanes.
// ONE barrier/iter; partials double-buffered at stride 64 (2-way = free).
// Exit: lane l of every wave holds U[l], V[l].
__device__ __forceinline__ void sinkhorn_rl(const float (&xR)[16], const float (&xC)[16],
    float& U, float& V, float* __restrict__ pp /*2*512*/, int l, int wu, int jb) {
  U = 0.f; V = 0.f;
#pragma unroll 1
  for (int it = 0; it < 20; ++it) {
    const bool row = (it & 1) == 0;
    float t[16];
    if (row) {
#pragma unroll
      for (int j = 0; j < 16; ++j) t[j] = xR[j] - rdlane(V, jb + j);
    } else {
#pragma unroll
      for (int j = 0; j < 16; ++j) t[j] = xC[j] - rdlane(U, jb + j);
    }
    float a0 = fmaxf(t[0], t[1]),  a1 = fmaxf(t[2], t[3]);
    float a2 = fmaxf(t[4], t[5]),  a3 = fmaxf(t[6], t[7]);
    a0 = fmaxf(a0, fmaxf(t[8], t[9]));   a1 = fmaxf(a1, fmaxf(t[10], t[11]));
    a2 = fmaxf(a2, fmaxf(t[12], t[13])); a3 = fmaxf(a3, fmaxf(t[14], t[15]));
    const float mx = fmaxf(fmaxf(a0, a1), fmaxf(a2, a3));
    float s0 = 0.f, s1 = 0.f, s2 = 0.f, s3 = 0.f;
#pragma unroll
    for (int j = 0; j < 16; j += 4) {
      s0 += __expf(t[j] - mx);     s1 += __expf(t[j + 1] - mx);
      s2 += __expf(t[j + 2] - mx); s3 += __expf(t[j + 3] - mx);
    }
    const float sm = (s0 + s1) + (s2 + s3);
    float* buf = pp + (it & 1) * 512;
    buf[wu * 64 + l] = mx;                         // stride-64: 2-way = free
    buf[256 + wu * 64 + l] = sm;
    __syncthreads();
    const float m0 = buf[l],       m1 = buf[64 + l];
    const float m2 = buf[128 + l], m3 = buf[192 + l];
    const float q0 = buf[256 + l], q1 = buf[320 + l];
    const float q2 = buf[384 + l], q3 = buf[448 + l];
    const float mM = fmaxf(fmaxf(m0, m1), fmaxf(m2, m3));
    const float ss = q0 * __expf(m0 - mM) + q1 * __expf(m1 - mM)
                   + q2 * __expf(m2 - mM) + q3 * __expf(m3 - mM);
    const float lse = mM + __logf(ss);
    if (row) U = lse; else V = lse;
  }
}

// ---------- layer-0 transform: deg from maskT popcounts, disv, g hi/lo, xselfT ----------
__global__ __launch_bounds__(256) void k_xform0(const float* __restrict__ K,
    const unsigned long long* __restrict__ maskT,
    const float* __restrict__ cw, const float* __restrict__ cb,
    const float* __restrict__ sw, const float* __restrict__ sb,
    float* __restrict__ disv,
    __hip_bfloat16* __restrict__ gHi, __hip_bfloat16* __restrict__ gLo,
    float* __restrict__ xselfT) {
  __shared__ float pdeg[4][64];
  const int lane = threadIdx.x & 63;
  const int wv = threadIdx.x >> 6;
  const int s = blockIdx.x * 64 + lane;
  unsigned cnt = 0;
#pragma unroll
  for (int q = 0; q < 16; ++q)
    cnt += (unsigned)__popcll(maskT[(size_t)(wv * 16 + q) * NN + s]);
  pdeg[wv][lane] = (float)cnt;
  __syncthreads();
  const float ds = rsqrtf(pdeg[0][lane] + pdeg[1][lane] + pdeg[2][lane] + pdeg[3][lane]);
  if (wv == 0) disv[s] = ds;
  const float xv = K[(size_t)s * NN + s];          // diag(K)
#pragma unroll
  for (int i = 0; i < 16; ++i) {
    const int c = wv * 16 + i;
    const float gv = ds * xv * cw[c];
    const __hip_bfloat16 hi = __float2bfloat16(gv);
    gHi[(size_t)c * NN + s] = hi;
    gLo[(size_t)c * NN + s] = __float2bfloat16(gv - __bfloat162float(hi));
    xselfT[(size_t)c * NN + s] = xv * sw[c] + sb[c] + cb[c];
  }
}

// ---------- layer transform: rl sinkhorn + FMA + rank-1 sk fold ----------
// grid (64, 2): blockIdx.x = s-tile, blockIdx.y = 32-channel half. 256 threads.
__global__ __launch_bounds__(256, 1) void k_xform(const float* __restrict__ v,
    const float* __restrict__ vT,
    const float* __restrict__ xoutT, const float* __restrict__ disv,
    const float* __restrict__ cw, const float* __restrict__ cb,
    const float* __restrict__ sw, const float* __restrict__ sb,
    __hip_bfloat16* __restrict__ gHi, __hip_bfloat16* __restrict__ gLo,
    float* __restrict__ xselfT) {
  __shared__ __align__(16) float pp[2 * 512];
  __shared__ float xt[64][64];                     // raw xout
  __shared__ float wcl[64 * 32], wsl[64 * 32];     // [k][c-local]
  const int tid = threadIdx.x;
  const int l = tid & 63;
  const int wu = __builtin_amdgcn_readfirstlane(tid >> 6);   // SGPR wave id
  const int jb = wu * 16;
  const int s = blockIdx.x * 64 + l;
  const int cbase = blockIdx.y * 32;
  // ---- sinkhorn input into registers (tiny, L2-resident) ----
  float xR[16], xC[16];
#pragma unroll
  for (int q = 0; q < 4; ++q) {
    *(f32x4*)&xR[4 * q] = *(const f32x4*)&v[l * 64 + jb + 4 * q] * 20.0f;
    *(f32x4*)&xC[4 * q] = *(const f32x4*)&vT[l * 64 + jb + 4 * q] * 20.0f;
  }
  // ---- stage xt + weight slab (synced by sinkhorn's first barrier) ----
#pragma unroll
  for (int r = 0; r < 16; ++r)
    xt[jb + r][l] = xoutT[(size_t)(jb + r) * NN + s];
#pragma unroll
  for (int q = 0; q < 8; ++q) {
    const int e = wu * 512 + q * 64 + l;           // e = k*32 + cl
    const int k = e >> 5, cl = e & 31;
    wcl[e] = cw[k * 64 + cbase + cl];
    wsl[e] = sw[k * 64 + cbase + cl];
  }
  float U, V;
  sinkhorn_rl(xR, xC, U, V, pp, l, wu, jb);
  // ---- FMA: 8 channels per wave; float4 broadcast weight reads ----
  const int cl0 = wu * 8;
  float accC[8], accS[8], csum[8], ssum[8];
#pragma unroll
  for (int i = 0; i < 8; ++i) { accC[i] = 0.f; accS[i] = 0.f; csum[i] = 0.f; ssum[i] = 0.f; }
  for (int k = 0; k < 64; ++k) {
    const float xv = xt[k][l];
    const f32x4 wcA = *(const f32x4*)&wcl[k * 32 + cl0];
    const f32x4 wcB = *(const f32x4*)&wcl[k * 32 + cl0 + 4];
    const f32x4 wsA = *(const f32x4*)&wsl[k * 32 + cl0];
    const f32x4 wsB = *(const f32x4*)&wsl[k * 32 + cl0 + 4];
#pragma unroll
    for (int i = 0; i < 4; ++i) {
      accC[i]     = fmaf(xv, wcA[i], accC[i]);     csum[i]     += wcA[i];
      accC[i + 4] = fmaf(xv, wcB[i], accC[i + 4]); csum[i + 4] += wcB[i];
      accS[i]     = fmaf(xv, wsA[i], accS[i]);     ssum[i]     += wsA[i];
      accS[i + 4] = fmaf(xv, wsB[i], accS[i + 4]); ssum[i + 4] += wsB[i];
    }
  }
  // ---- epilogue: sk from duals (SGPR readlane for U[bx]), rank-1 sk fold ----
  const int bx = blockIdx.x;
  const float Ubx = rdlane(U, bx);                 // SGPR index, no waterfall
  const float skv = __expf(20.0f * v[bx * 64 + l] - Ubx - V);
  const float ds = disv[s];
#pragma unroll
  for (int i = 0; i < 8; ++i) {
    const int c = cbase + cl0 + i;
    const float gv = ds * (accC[i] + skv * csum[i]);
    const __hip_bfloat16 hi = __float2bfloat16(gv);
    gHi[(size_t)c * NN + s] = hi;
    gLo[(size_t)c * NN + s] = __float2bfloat16(gv - __bfloat162float(hi));
    xselfT[(size_t)c * NN + s] = accS[i] + skv * ssum[i] + sb[c] + cb[c];
  }
}

// ---------- MFMA masked aggregation + in-block combine (+ final-score fold on last layer) ----------
__global__ __launch_bounds__(512) void k_agg(const unsigned long long* __restrict__ maskT,
    const __hip_bfloat16* __restrict__ gHi, const __hip_bfloat16* __restrict__ gLo,
    const float* __restrict__ xselfT, const float* __restrict__ disv,
    const float* __restrict__ kw, const float* __restrict__ kb,
    const float* __restrict__ fw, const float* __restrict__ fb,
    float* __restrict__ xoutT, float* __restrict__ v, float* __restrict__ vT,
    float* __restrict__ sbF) {
  const int tid = threadIdx.x;
  const int lane = tid & 63;
  const int wv = tid >> 6;           // 0..7
  const int mtile = wv & 3;          // channel 16-group
  const int ks = wv >> 2;            // K-split 0/1
  const int l15 = lane & 15;
  const int h = lane >> 4;           // 0..3
  const int d = blockIdx.x * 16 + l15;
  const int ch = mtile * 16 + l15;   // A-operand row (channel)
  const short* __restrict__ gh = (const short*)gHi;
  const short* __restrict__ gl = (const short*)gLo;
  f32x4 acch = {0.f, 0.f, 0.f, 0.f};
  f32x4 accl = {0.f, 0.f, 0.f, 0.f};
  const int c0 = ks * 32;
#pragma unroll 4
  for (int c = c0; c < c0 + 32; ++c) {
    const unsigned long long w = maskT[(size_t)c * NN + d];
    const unsigned half0 = (unsigned)w, half1 = (unsigned)(w >> 32);
#pragma unroll
    for (int t = 0; t < 2; ++t) {
      const unsigned half = t ? half1 : half0;
      const unsigned hb = (half >> (8 * h)) & 0xFFu;
      s16x8 bfr;
#pragma unroll
      for (int j = 0; j < 8; ++j)
        bfr[j] = (short)(((hb >> j) & 1u) * 0x3F80u);   // bit -> bf16 1.0/0.0
      const size_t abase = (size_t)ch * NN + (size_t)(c * 64 + t * 32 + 8 * h);
      const s16x8 ah = *(const s16x8*)(gh + abase);
      const s16x8 al = *(const s16x8*)(gl + abase);
      acch = __builtin_amdgcn_mfma_f32_16x16x32_bf16(ah, bfr, acch, 0, 0, 0);
      accl = __builtin_amdgcn_mfma_f32_16x16x32_bf16(al, bfr, accl, 0, 0, 0);
    }
  }
  __shared__ float rbuf[4][64][5];
  __shared__ float vred[16][17];
  __shared__ float vred2[16][17];
  f32x4 tot;
#pragma unroll
  for (int r = 0; r < 4; ++r) tot[r] = acch[r] + accl[r];
  if (ks == 1) {
#pragma unroll
    for (int r = 0; r < 4; ++r) rbuf[mtile][lane][r] = tot[r];
  }
  __syncthreads();
  if (ks == 0) {
    // C/D layout: col = lane&15 (=d), row = (lane>>4)*4 + reg (=channel in mtile)
    const float dd = disv[d];
    float p = 0.f, p2 = 0.f;
#pragma unroll
    for (int r = 0; r < 4; ++r) {
      const int chr = mtile * 16 + h * 4 + r;
      const float xo = xselfT[(size_t)chr * NN + d] + dd * (tot[r] + rbuf[mtile][lane][r]);
      xoutT[(size_t)chr * NN + d] = xo;
      p = fmaf(xo, kw[chr], p);
      p2 = fmaf(xo, fw[chr], p2);    // final-score partial (used only on last layer)
    }
    vred[l15][mtile * 4 + h] = p;
    vred2[l15][mtile * 4 + h] = p2;
  }
  __syncthreads();
  if (tid < 16) {
    float sum = kb[0];
#pragma unroll
    for (int q = 0; q < 16; ++q) sum += vred[tid][q];
    const int d2 = blockIdx.x * 16 + tid;
    v[d2] = sum;                                   // flat: row-major S0
    vT[(d2 & 63) * 64 + (d2 >> 6)] = sum;          // transposed
    if (sbF != nullptr) {                          // last layer: base scores, flat
      float sum2 = fb[0];
#pragma unroll
      for (int q = 0; q < 16; ++q) sum2 += vred2[tid][q];
      sbF[d2] = sum2;
    }
  }
}

// ---------- final: rl sinkhorn(sk2) -> fold (LDS swap) -> rl sinkhorn -> out ----------
__global__ __launch_bounds__(256, 1) void k_final(const float* __restrict__ v,
    const float* __restrict__ vT, const float* __restrict__ sbF,
    const float* __restrict__ fw, float* __restrict__ out) {
  __shared__ __align__(16) float pp[2 * 512];
  __shared__ __align__(16) float scR[64 * 68];     // folded S row-major
  __shared__ __align__(16) float scT[64 * 68];     // folded S col-major
  __shared__ float fwl[64];
  const int tid = threadIdx.x;
  const int l = tid & 63;
  const int wu = __builtin_amdgcn_readfirstlane(tid >> 6);   // SGPR wave id
  const int jb = wu * 16;
  float xR[16], xC[16];
#pragma unroll
  for (int q = 0; q < 4; ++q) {
    *(f32x4*)&xR[4 * q] = *(const f32x4*)&v[l * 64 + jb + 4 * q] * 20.0f;
    *(f32x4*)&xC[4 * q] = *(const f32x4*)&vT[l * 64 + jb + 4 * q] * 20.0f;
  }
  if (tid < 64) fwl[tid] = fw[tid];
  float U1, V1;
  sinkhorn_rl(xR, xC, U1, V1, pp, l, wu, jb);      // sk2 duals (lane l of every wave)
  float sumw = 0.f;
#pragma unroll
  for (int k = 0; k < 64; ++k) sumw += fwl[k];     // broadcast reads
  // ---- fold: S[i1=n&63][i2=n>>6] = (scores[n] + sk2[n]*sumw)*20 ----
#pragma unroll
  for (int k = 0; k < 16; ++k) {
    const int n = k * 256 + tid;                   // r2 = n>>6 uniform per iter
    const int r2 = 4 * k + wu;                     // SGPR
    const float u1r2 = rdlane(U1, r2);             // SGPR readlane
    const float sk2 = __expf(20.0f * v[n] - u1r2 - V1);
    const float val = (sbF[n] + sk2 * sumw) * 20.0f;
    scR[l * 68 + r2] = val;                        // S[i1=l][i2=r2]
    scT[r2 * 68 + l] = val;
  }
  __syncthreads();
  // ---- reload regs in both orientations (stride-68 b128: conflict-free) ----
#pragma unroll
  for (int q = 0; q < 4; ++q) {
    *(f32x4*)&xR[4 * q] = *(const f32x4*)&scR[l * 68 + jb + 4 * q];
    *(f32x4*)&xC[4 * q] = *(const f32x4*)&scT[l * 68 + jb + 4 * q];
  }
  float U2, V2;
  sinkhorn_rl(xR, xC, U2, V2, pp, l, wu, jb);
  // ---- output: out[i1*64+i2] = exp(S - U2[i1] - V2[i2]) ----
#pragma unroll
  for (int q = 0; q < 16; ++q) {
    const int e = q * 256 + tid;                   // i1 = 4q+wu (SGPR), i2 = l
    const int i1 = 4 * q + wu;
    const float u2i1 = rdlane(U2, i1);
    out[e] = __expf(scR[i1 * 68 + l] - u2i1 - V2);
  }
}

extern "C" void kernel_launch(void* const* d_in, const int* in_sizes, int n_in,
                              void* d_out, int out_size, void* d_ws, size_t ws_size,
                              hipStream_t stream) {
  const float* K = (const float*)d_in[0];
  const float* cw[3] = {(const float*)d_in[4],  (const float*)d_in[10], (const float*)d_in[16]};
  const float* cb[3] = {(const float*)d_in[5],  (const float*)d_in[11], (const float*)d_in[17]};
  const float* sw[3] = {(const float*)d_in[6],  (const float*)d_in[12], (const float*)d_in[18]};
  const float* sb[3] = {(const float*)d_in[7],  (const float*)d_in[13], (const float*)d_in[19]};
  const float* kw[3] = {(const float*)d_in[8],  (const float*)d_in[14], (const float*)d_in[20]};
  const float* kb[3] = {(const float*)d_in[9],  (const float*)d_in[15], (const float*)d_in[21]};
  const float* fw = (const float*)d_in[22];
  const float* fb = (const float*)d_in[23];
  float* out = (float*)d_out;

  char* ws = (char*)d_ws;
  const size_t KB = 1024, MB = 1024 * 1024;
  float* disv               = (float*)(ws + 0);                   // 16 KB
  float* v                  = (float*)(ws + 16 * KB);             // 16 KB
  float* vT                 = (float*)(ws + 32 * KB);             // 16 KB
  float* sbF                = (float*)(ws + 48 * KB);             // 16 KB
  unsigned long long* maskT = (unsigned long long*)(ws + 64 * KB);// 2 MB
  __hip_bfloat16* gHi       = (__hip_bfloat16*)(ws + 64 * KB + 2 * MB);            // 512 KB
  __hip_bfloat16* gLo       = (__hip_bfloat16*)(ws + 64 * KB + 2 * MB + 512 * KB); // 512 KB
  float* xselfT             = (float*)(ws + 64 * KB + 3 * MB);    // 1 MB
  float* xoutT              = (float*)(ws + 64 * KB + 4 * MB);    // 1 MB
  (void)in_sizes; (void)n_in; (void)out_size; (void)ws_size;

  k_prep<<<dim3(16, 16), 256, 0, stream>>>(K, maskT);
  k_xform0<<<64, 256, 0, stream>>>(K, maskT, cw[0], cb[0], sw[0], sb[0],
                                   disv, gHi, gLo, xselfT);
  k_agg<<<256, 512, 0, stream>>>(maskT, gHi, gLo, xselfT, disv, kw[0], kb[0],
                                 fw, fb, xoutT, v, vT, nullptr);
  for (int l = 1; l < 3; ++l) {
    k_xform<<<dim3(64, 2), 256, 0, stream>>>(v, vT, xoutT, disv, cw[l], cb[l], sw[l], sb[l],
                                             gHi, gLo, xselfT);
    k_agg<<<256, 512, 0, stream>>>(maskT, gHi, gLo, xselfT, disv, kw[l], kb[l],
                                   fw, fb, xoutT, v, vT, (l == 2) ? sbF : nullptr);
  }
  k_final<<<1, 256, 0, stream>>>(v, vT, sbF, fw, out);
}